// Round 5
// baseline (546.011 us; speedup 1.0000x reference)
//
#include <hip/hip_runtime.h>
#include <hip/hip_bf16.h>

#define EMB 1024
#define NH 16
#define HD 64
#define BATCH 8
#define SEQ 1024
#define ROWS (BATCH*SEQ)   // 8192

typedef unsigned short ushort_t;
typedef __attribute__((ext_vector_type(8))) short bf16x8;
typedef __attribute__((ext_vector_type(4))) float f32x4;
typedef __attribute__((ext_vector_type(16))) float f32x16;

__device__ __forceinline__ float bf2f(ushort_t u){
    union { unsigned int i; float f; } v; v.i = ((unsigned int)u) << 16; return v.f;
}
__device__ __forceinline__ ushort_t f2bf(float f){
    unsigned int u = __float_as_uint(f);
    unsigned int r = (u + 0x7FFFu + ((u >> 16) & 1u)) >> 16;
    return (ushort_t)r;
}
__device__ __forceinline__ void gload16(const ushort_t* g, ushort_t* l){
    __builtin_amdgcn_global_load_lds(
        (const __attribute__((address_space(1))) void*)g,
        (__attribute__((address_space(3))) void*)l,
        16, 0, 0);
}
// exact-erf GELU via A&S 7.1.26 (|err| < 1.5e-7)
__device__ __forceinline__ float gelu_f(float v){
    float x = fabsf(v) * 0.70710678118654752f;
    float t = __builtin_amdgcn_rcpf(1.0f + 0.3275911f * x);
    float poly = t*(0.254829592f + t*(-0.284496736f + t*(1.421413741f + t*(-1.453152027f + t*1.061405429f))));
    float erfa = 1.0f - poly * __expf(-x*x);
    float erfv = (v >= 0.f) ? erfa : -erfa;
    return 0.5f * v * (1.0f + erfv);
}

// ---------------- weight transpose + convert (f32 [K][N] -> bf16 [N][K]) ----------------
__global__ __launch_bounds__(256) void transpose_w(const float* __restrict__ in,
                                                   ushort_t* __restrict__ out,
                                                   int K, int N){
    __shared__ ushort_t t[32][33];
    int tx = threadIdx.x & 31, ty = threadIdx.x >> 5;
    int bx = blockIdx.x, by = blockIdx.y;
    #pragma unroll
    for (int r = 0; r < 4; ++r)
        t[ty + r*8][tx] = f2bf(in[(size_t)(by*32 + ty + r*8) * N + bx*32 + tx]);
    __syncthreads();
    #pragma unroll
    for (int r = 0; r < 4; ++r)
        out[(size_t)(bx*32 + ty + r*8) * K + by*32 + tx] = t[tx][ty + r*8];
}

// ---------------- LayerNorm (row = 1024), f32 in -> bf16 out ----------------
__global__ __launch_bounds__(256) void ln_kernel(const float* __restrict__ xin,
                                                 const float* __restrict__ g,
                                                 const float* __restrict__ bia,
                                                 ushort_t* __restrict__ out){
    int row = blockIdx.x;
    int tid = threadIdx.x;
    const float* x = xin + (size_t)row * EMB;
    float4 f = *(const float4*)(x + tid*4);
    float v[4] = {f.x, f.y, f.z, f.w};
    float s = v[0]+v[1]+v[2]+v[3];
    float q = v[0]*v[0]+v[1]*v[1]+v[2]*v[2]+v[3]*v[3];
    #pragma unroll
    for (int o = 32; o > 0; o >>= 1){ s += __shfl_down(s, o); q += __shfl_down(q, o); }
    __shared__ float ss[4], qq[4];
    __shared__ float mu_s, sc_s;
    int wave = tid >> 6, lane = tid & 63;
    if (lane == 0){ ss[wave] = s; qq[wave] = q; }
    __syncthreads();
    if (tid == 0){
        float S = ss[0]+ss[1]+ss[2]+ss[3];
        float Q = qq[0]+qq[1]+qq[2]+qq[3];
        float mu = S * (1.0f/EMB);
        float var = Q * (1.0f/EMB) - mu*mu;
        mu_s = mu; sc_s = rsqrtf(var + 1e-5f);
    }
    __syncthreads();
    float mu = mu_s, sc = sc_s;
    float4 gu = *(const float4*)(g + tid*4);
    float4 bu = *(const float4*)(bia + tid*4);
    ushort4 o4;
    o4.x = f2bf((v[0]-mu)*sc*gu.x + bu.x);
    o4.y = f2bf((v[1]-mu)*sc*gu.y + bu.y);
    o4.z = f2bf((v[2]-mu)*sc*gu.z + bu.z);
    o4.w = f2bf((v[3]-mu)*sc*gu.w + bu.w);
    *(ushort4*)(out + (size_t)row*EMB + tid*4) = o4;
}

// ---------------- GEMM (m97 + XOR swizzle + 32x32x16 MFMA) ----------------
// BM=128 fixed. BN in {128,64}. Wave grid WMW x WNW (WMW*WNW==4).
// LDS chunk c (16B) of row r holds global chunk c ^ (r&7) -> conflict-free b128 reads.
// MODE 0: plain -> bf16 | 1: +bias+resid -> f32 | 2: +bias+GELU -> bf16 | 3: +bias+resid -> f32
template<int MODE, int BN, int WMW, int WNW>
__global__ __launch_bounds__(256) void gemm_kernel(const ushort_t* __restrict__ A,
                                                   const ushort_t* __restrict__ Bt,
                                                   const float* __restrict__ bias,
                                                   const float* __restrict__ resid,
                                                   void* __restrict__ out,
                                                   int M, int N, int K){
    constexpr int TM = 128 / WMW;        // wave tile M
    constexpr int TN = BN / WNW;         // wave tile N
    constexpr int NTM = TM / 32;
    constexpr int NTN = TN / 32;
    constexpr int BROWS = BN / 4;        // B rows staged per wave

    __shared__ ushort_t As[128*64];
    __shared__ ushort_t Bs[BN*64];
    int tid = threadIdx.x;
    int lane = tid & 63, wave = tid >> 6;
    int l31 = lane & 31, half = lane >> 5;
    int wm = wave / WNW, wn = wave % WNW;
    int m0 = blockIdx.y * 128, n0 = blockIdx.x * BN;

    f32x16 acc[NTM][NTN];
    #pragma unroll
    for (int i=0;i<NTM;i++)
        #pragma unroll
        for (int j=0;j<NTN;j++)
            #pragma unroll
            for (int r=0;r<16;r++) acc[i][j][r] = 0.f;

    int lr  = lane >> 3;        // row within 8-row group
    int lch = lane & 7;         // destination LDS chunk
    const ushort_t* gA = A  + (size_t)(m0 + wave*32    + lr)*K + (lch ^ lr)*8;
    const ushort_t* gB = Bt + (size_t)(n0 + wave*BROWS + lr)*K + (lch ^ lr)*8;
    ushort_t* lA = &As[(wave*32)*64];
    ushort_t* lB = &Bs[(wave*BROWS)*64];
    int sx = lane & 7;          // fragment-read swizzle (row&7 == lane&7)

    for (int k0 = 0; k0 < K; k0 += 64){
        #pragma unroll
        for (int i = 0; i < 4; ++i)
            gload16(gA + (size_t)(i*8)*K + k0, lA + i*8*64);
        #pragma unroll
        for (int i = 0; i < BROWS/8; ++i)
            gload16(gB + (size_t)(i*8)*K + k0, lB + i*8*64);
        __syncthreads();
        #pragma unroll
        for (int s = 0; s < 4; ++s){
            int ch = ((s<<1) | half) ^ sx;
            bf16x8 af[NTM], bfr[NTN];
            #pragma unroll
            for (int i=0;i<NTM;i++) af[i]  = *(const bf16x8*)&As[(wm*TM + i*32 + l31)*64 + ch*8];
            #pragma unroll
            for (int j=0;j<NTN;j++) bfr[j] = *(const bf16x8*)&Bs[(wn*TN + j*32 + l31)*64 + ch*8];
            #pragma unroll
            for (int i=0;i<NTM;i++)
                #pragma unroll
                for (int j=0;j<NTN;j++)
                    acc[i][j] = __builtin_amdgcn_mfma_f32_32x32x16_bf16(af[i], bfr[j], acc[i][j], 0,0,0);
        }
        __syncthreads();
    }

    // C/D layout (32x32): col = lane&31, row = (reg&3) + 8*(reg>>2) + 4*(lane>>5)
    int rowoff = 4*half;
    #pragma unroll
    for (int i=0;i<NTM;i++){
        #pragma unroll
        for (int j=0;j<NTN;j++){
            int n = n0 + wn*TN + j*32 + l31;
            #pragma unroll
            for (int reg=0; reg<16; ++reg){
                int m = m0 + wm*TM + i*32 + (reg&3) + 8*(reg>>2) + rowoff;
                float v = acc[i][j][reg];
                size_t idx = (size_t)m*N + n;
                if (MODE == 0){
                    ((ushort_t*)out)[idx] = f2bf(v);
                } else if (MODE == 1){
                    v += bias[n] + resid[idx];
                    ((float*)out)[idx] = v;
                } else if (MODE == 2){
                    v += bias[n];
                    ((ushort_t*)out)[idx] = f2bf(gelu_f(v));
                } else {
                    v += bias[n] + resid[idx];
                    ((float*)out)[idx] = v;
                }
            }
        }
    }
}

// ---------------- Flash attention (causal), D=64, KV tile = 64, paired q-tiles ----------------
__global__ __launch_bounds__(256) void attn_kernel(const ushort_t* __restrict__ qkv,
                                                   ushort_t* __restrict__ attn_out){
    __shared__ ushort_t Qs[128][72];
    __shared__ ushort_t Ks[64][72];
    __shared__ ushort_t Vts[64][72];   // V transposed + XOR-swizzled
    __shared__ ushort_t Ps[128][72];

    int tid = threadIdx.x;
    int lane = tid & 63, wave = tid >> 6;
    int quad = lane >> 4, l15 = lane & 15;
    int pair = blockIdx.x;         // 0..3
    int bh = blockIdx.y;           // 0..127
    int b = bh >> 4, h = bh & 15;
    size_t tb = (size_t)b * SEQ;

    int tr = tid >> 3;             // 0..31
    int tc = (tid & 7) * 8;        // 0..56
    int sw_w = tid & 7;            // V-write swizzle

    for (int t = 0; t < 2; ++t){
        int qi = t ? (7 - pair) : pair;

        #pragma unroll
        for (int p = 0; p < 4; ++p){
            int r = tr + p*32;
            size_t tok = tb + qi*128 + r;
            *(bf16x8*)&Qs[r][tc] = *(const bf16x8*)(qkv + tok*3072 + h*64 + tc);
        }

        f32x4 o_acc[2][4];
        #pragma unroll
        for (int mt=0;mt<2;mt++)
            #pragma unroll
            for (int nt=0;nt<4;nt++) o_acc[mt][nt] = (f32x4){0.f,0.f,0.f,0.f};
        float m_st[2][4], l_st[2][4];
        #pragma unroll
        for (int mt=0;mt<2;mt++)
            #pragma unroll
            for (int r=0;r<4;r++){ m_st[mt][r] = -1e30f; l_st[mt][r] = 0.f; }

        int nj = 2*qi + 2;
        for (int j = 0; j < nj; ++j){
            #pragma unroll
            for (int p = 0; p < 2; ++p){
                int r = tr + p*32;
                size_t tok = tb + j*64 + r;
                *(bf16x8*)&Ks[r][tc] = *(const bf16x8*)(qkv + tok*3072 + 1024 + h*64 + tc);
                bf16x8 vv = *(const bf16x8*)(qkv + tok*3072 + 2048 + h*64 + tc);
                int kcol = r ^ (sw_w << 3);
                #pragma unroll
                for (int c = 0; c < 8; ++c) Vts[tc + c][kcol] = (ushort_t)vv[c];
            }
            __syncthreads();

            f32x4 s_acc[2][4];
            #pragma unroll
            for (int mt=0;mt<2;mt++)
                #pragma unroll
                for (int nt=0;nt<4;nt++) s_acc[mt][nt] = (f32x4){0.f,0.f,0.f,0.f};
            #pragma unroll
            for (int kf = 0; kf < 2; ++kf){
                bf16x8 aq[2], bk[4];
                #pragma unroll
                for (int mt=0;mt<2;mt++) aq[mt] = *(const bf16x8*)&Qs[wave*32 + mt*16 + l15][kf*32 + quad*8];
                #pragma unroll
                for (int nt=0;nt<4;nt++) bk[nt] = *(const bf16x8*)&Ks[nt*16 + l15][kf*32 + quad*8];
                #pragma unroll
                for (int mt=0;mt<2;mt++)
                    #pragma unroll
                    for (int nt=0;nt<4;nt++)
                        s_acc[mt][nt] = __builtin_amdgcn_mfma_f32_16x16x32_bf16(aq[mt], bk[nt], s_acc[mt][nt], 0,0,0);
            }

            bool need_mask = (j >= 2*qi);
            #pragma unroll
            for (int mt=0;mt<2;mt++)
                #pragma unroll
                for (int nt=0;nt<4;nt++)
                    #pragma unroll
                    for (int r=0;r<4;r++){
                        float s = s_acc[mt][nt][r] * 0.125f;
                        if (need_mask){
                            int qg = qi*128 + wave*32 + mt*16 + quad*4 + r;
                            int kg = j*64 + nt*16 + l15;
                            if (kg > qg) s = -1e30f;
                        }
                        s_acc[mt][nt][r] = s;
                    }

            #pragma unroll
            for (int mt=0;mt<2;mt++){
                #pragma unroll
                for (int r=0;r<4;r++){
                    float rm = s_acc[mt][0][r];
                    #pragma unroll
                    for (int nt=1;nt<4;nt++) rm = fmaxf(rm, s_acc[mt][nt][r]);
                    rm = fmaxf(rm, __shfl_xor(rm, 1));
                    rm = fmaxf(rm, __shfl_xor(rm, 2));
                    rm = fmaxf(rm, __shfl_xor(rm, 4));
                    rm = fmaxf(rm, __shfl_xor(rm, 8));
                    float mnew = fmaxf(m_st[mt][r], rm);
                    float alpha = __expf(m_st[mt][r] - mnew);
                    float rsum = 0.f;
                    #pragma unroll
                    for (int nt=0;nt<4;nt++){
                        float p = __expf(s_acc[mt][nt][r] - mnew);
                        s_acc[mt][nt][r] = p;
                        rsum += p;
                    }
                    rsum += __shfl_xor(rsum, 1);
                    rsum += __shfl_xor(rsum, 2);
                    rsum += __shfl_xor(rsum, 4);
                    rsum += __shfl_xor(rsum, 8);
                    l_st[mt][r] = l_st[mt][r]*alpha + rsum;
                    m_st[mt][r] = mnew;
                    #pragma unroll
                    for (int nt=0;nt<4;nt++) o_acc[mt][nt][r] *= alpha;
                }
            }

            #pragma unroll
            for (int mt=0;mt<2;mt++)
                #pragma unroll
                for (int nt=0;nt<4;nt++)
                    #pragma unroll
                    for (int r=0;r<4;r++)
                        Ps[wave*32 + mt*16 + quad*4 + r][nt*16 + l15] = f2bf(s_acc[mt][nt][r]);

            #pragma unroll
            for (int kf = 0; kf < 2; ++kf){
                bf16x8 ap[2], bv[4];
                #pragma unroll
                for (int mt=0;mt<2;mt++) ap[mt] = *(const bf16x8*)&Ps[wave*32 + mt*16 + l15][kf*32 + quad*8];
                #pragma unroll
                for (int nt=0;nt<4;nt++){
                    int d = nt*16 + l15;
                    int col = (kf*32 + quad*8) ^ (((d >> 3) & 7) << 3);
                    bv[nt] = *(const bf16x8*)&Vts[d][col];
                }
                #pragma unroll
                for (int mt=0;mt<2;mt++)
                    #pragma unroll
                    for (int nt=0;nt<4;nt++)
                        o_acc[mt][nt] = __builtin_amdgcn_mfma_f32_16x16x32_bf16(ap[mt], bv[nt], o_acc[mt][nt], 0,0,0);
            }
            __syncthreads();
        }

        #pragma unroll
        for (int mt=0;mt<2;mt++)
            #pragma unroll
            for (int r=0;r<4;r++){
                float inv = 1.0f / l_st[mt][r];
                size_t tok = tb + qi*128 + wave*32 + mt*16 + quad*4 + r;
                #pragma unroll
                for (int nt=0;nt<4;nt++)
                    attn_out[tok*EMB + h*64 + nt*16 + l15] = f2bf(o_acc[mt][nt][r] * inv);
            }
    }
}

extern "C" void kernel_launch(void* const* d_in, const int* in_sizes, int n_in,
                              void* d_out, int out_size, void* d_ws, size_t ws_size,
                              hipStream_t stream){
    const float* x      = (const float*)d_in[0];
    const float* ln1_g  = (const float*)d_in[1];
    const float* ln1_b  = (const float*)d_in[2];
    const float* wq     = (const float*)d_in[3];
    const float* wk     = (const float*)d_in[4];
    const float* wv     = (const float*)d_in[5];
    const float* w_proj = (const float*)d_in[6];
    const float* b_proj = (const float*)d_in[7];
    const float* ln2_g  = (const float*)d_in[8];
    const float* ln2_b  = (const float*)d_in[9];
    const float* w1     = (const float*)d_in[10];
    const float* b1     = (const float*)d_in[11];
    const float* w2     = (const float*)d_in[12];
    const float* b2     = (const float*)d_in[13];
    float* outp = (float*)d_out;

    char* ws = (char*)d_ws;
    size_t off = 0;
    auto alloc = [&](size_t bytes)->char*{ char* p = ws + off; off += (bytes + 255) & ~255ULL; return p; };
    ushort_t* wqkv_t = (ushort_t*)alloc((size_t)3072*1024*2);
    ushort_t* wproj_t= (ushort_t*)alloc((size_t)1024*1024*2);
    ushort_t* w1_t   = (ushort_t*)alloc((size_t)4096*1024*2);
    ushort_t* w2_t   = (ushort_t*)alloc((size_t)1024*4096*2);
    ushort_t* qkv    = (ushort_t*)alloc((size_t)ROWS*3072*2);
    ushort_t* hbuf   = (ushort_t*)alloc((size_t)ROWS*1024*2);
    float*    out32  = (float*)  alloc((size_t)ROWS*1024*4);
    ushort_t* mid    = (ushort_t*)alloc((size_t)ROWS*4096*2);
    ushort_t* h1 = hbuf;
    ushort_t* attn = hbuf;   // h1 dead after qkv GEMM
    ushort_t* h2 = qkv;      // qkv dead after attention

    dim3 blk(256);
    transpose_w<<<dim3(32,32),  blk, 0, stream>>>(wq,     wqkv_t,               1024, 1024);
    transpose_w<<<dim3(32,32),  blk, 0, stream>>>(wk,     wqkv_t + 1024*1024,   1024, 1024);
    transpose_w<<<dim3(32,32),  blk, 0, stream>>>(wv,     wqkv_t + 2*1024*1024, 1024, 1024);
    transpose_w<<<dim3(32,32),  blk, 0, stream>>>(w_proj, wproj_t,              1024, 1024);
    transpose_w<<<dim3(128,32), blk, 0, stream>>>(w1,     w1_t,                 1024, 4096);
    transpose_w<<<dim3(32,128), blk, 0, stream>>>(w2,     w2_t,                 4096, 1024);

    ln_kernel<<<ROWS, blk, 0, stream>>>(x, ln1_g, ln1_b, h1);
    gemm_kernel<0,128,2,2><<<dim3(3072/128, ROWS/128), blk, 0, stream>>>(h1, wqkv_t, nullptr, nullptr, qkv, ROWS, 3072, 1024);
    attn_kernel<<<dim3(4,128), blk, 0, stream>>>(qkv, attn);
    gemm_kernel<1, 64,4,1><<<dim3(1024/64,  ROWS/128), blk, 0, stream>>>(attn, wproj_t, b_proj, x, out32, ROWS, 1024, 1024);
    ln_kernel<<<ROWS, blk, 0, stream>>>(out32, ln2_g, ln2_b, h2);
    gemm_kernel<2,128,2,2><<<dim3(4096/128, ROWS/128), blk, 0, stream>>>(h2, w1_t, b1, nullptr, mid, ROWS, 4096, 1024);
    gemm_kernel<3, 64,4,1><<<dim3(1024/64,  ROWS/128), blk, 0, stream>>>(mid, w2_t, b2, out32, outp, ROWS, 1024, 4096);
}

// Round 6
// 489.474 us; speedup vs baseline: 1.1155x; 1.1155x over previous
//
#include <hip/hip_runtime.h>
#include <hip/hip_bf16.h>

#define EMB 1024
#define NH 16
#define HD 64
#define BATCH 8
#define SEQ 1024
#define ROWS (BATCH*SEQ)   // 8192
#define MT (ROWS/128)      // 64 m-tiles

typedef unsigned short ushort_t;
typedef __attribute__((ext_vector_type(8))) short bf16x8;
typedef __attribute__((ext_vector_type(4))) float f32x4;
typedef __attribute__((ext_vector_type(16))) float f32x16;

__device__ __forceinline__ float bf2f(ushort_t u){
    union { unsigned int i; float f; } v; v.i = ((unsigned int)u) << 16; return v.f;
}
__device__ __forceinline__ ushort_t f2bf(float f){
    unsigned int u = __float_as_uint(f);
    unsigned int r = (u + 0x7FFFu + ((u >> 16) & 1u)) >> 16;
    return (ushort_t)r;
}
__device__ __forceinline__ void gload16(const ushort_t* g, ushort_t* l){
    __builtin_amdgcn_global_load_lds(
        (const __attribute__((address_space(1))) void*)g,
        (__attribute__((address_space(3))) void*)l,
        16, 0, 0);
}
// exact-erf GELU via A&S 7.1.26 (|err| < 1.5e-7)
__device__ __forceinline__ float gelu_f(float v){
    float x = fabsf(v) * 0.70710678118654752f;
    float t = __builtin_amdgcn_rcpf(1.0f + 0.3275911f * x);
    float poly = t*(0.254829592f + t*(-0.284496736f + t*(1.421413741f + t*(-1.453152027f + t*1.061405429f))));
    float erfa = 1.0f - poly * __expf(-x*x);
    float erfv = (v >= 0.f) ? erfa : -erfa;
    return 0.5f * v * (1.0f + erfv);
}

// ---------------- weight transpose + convert (f32 [K][N] -> bf16 [N][K]) ----------------
__global__ __launch_bounds__(256) void transpose_w(const float* __restrict__ in,
                                                   ushort_t* __restrict__ out,
                                                   int K, int N){
    __shared__ ushort_t t[32][33];
    int tx = threadIdx.x & 31, ty = threadIdx.x >> 5;
    int bx = blockIdx.x, by = blockIdx.y;
    #pragma unroll
    for (int r = 0; r < 4; ++r)
        t[ty + r*8][tx] = f2bf(in[(size_t)(by*32 + ty + r*8) * N + bx*32 + tx]);
    __syncthreads();
    #pragma unroll
    for (int r = 0; r < 4; ++r)
        out[(size_t)(bx*32 + ty + r*8) * K + by*32 + tx] = t[tx][ty + r*8];
}

// ---------------- LayerNorm (row = 1024), f32 in -> bf16 out ----------------
__global__ __launch_bounds__(256) void ln_kernel(const float* __restrict__ xin,
                                                 const float* __restrict__ g,
                                                 const float* __restrict__ bia,
                                                 ushort_t* __restrict__ out){
    int row = blockIdx.x;
    int tid = threadIdx.x;
    const float* x = xin + (size_t)row * EMB;
    float4 f = *(const float4*)(x + tid*4);
    float v[4] = {f.x, f.y, f.z, f.w};
    float s = v[0]+v[1]+v[2]+v[3];
    float q = v[0]*v[0]+v[1]*v[1]+v[2]*v[2]+v[3]*v[3];
    #pragma unroll
    for (int o = 32; o > 0; o >>= 1){ s += __shfl_down(s, o); q += __shfl_down(q, o); }
    __shared__ float ss[4], qq[4];
    __shared__ float mu_s, sc_s;
    int wave = tid >> 6, lane = tid & 63;
    if (lane == 0){ ss[wave] = s; qq[wave] = q; }
    __syncthreads();
    if (tid == 0){
        float S = ss[0]+ss[1]+ss[2]+ss[3];
        float Q = qq[0]+qq[1]+qq[2]+qq[3];
        float mu = S * (1.0f/EMB);
        float var = Q * (1.0f/EMB) - mu*mu;
        mu_s = mu; sc_s = rsqrtf(var + 1e-5f);
    }
    __syncthreads();
    float mu = mu_s, sc = sc_s;
    float4 gu = *(const float4*)(g + tid*4);
    float4 bu = *(const float4*)(bia + tid*4);
    ushort4 o4;
    o4.x = f2bf((v[0]-mu)*sc*gu.x + bu.x);
    o4.y = f2bf((v[1]-mu)*sc*gu.y + bu.y);
    o4.z = f2bf((v[2]-mu)*sc*gu.z + bu.z);
    o4.w = f2bf((v[3]-mu)*sc*gu.w + bu.w);
    *(ushort4*)(out + (size_t)row*EMB + tid*4) = o4;
}

// ---------------- GEMM: 128x128 tile, 32x32x16 MFMA, XOR-swizzled LDS ----------------
// 1-D grid, mt = bid & 63 / nt = bid >> 6  => same-m blocks share an XCD (L2 A-reuse).
// LDS chunk c (16B) of row r holds global chunk c ^ (r&7) -> conflict-free b128 reads.
// MODE 0: plain -> bf16 | 1: +bias+resid -> f32 | 2: +bias+GELU -> bf16 | 3: +bias+resid -> f32
template<int MODE>
__global__ __launch_bounds__(256) void gemm_kernel(const ushort_t* __restrict__ A,
                                                   const ushort_t* __restrict__ Bt,
                                                   const float* __restrict__ bias,
                                                   const float* __restrict__ resid,
                                                   void* __restrict__ out,
                                                   int M, int N, int K){
    __shared__ ushort_t As[128*64];
    __shared__ ushort_t Bs[128*64];
    int tid = threadIdx.x;
    int lane = tid & 63, wave = tid >> 6;
    int l31 = lane & 31, half = lane >> 5;
    int wm = wave >> 1, wn = wave & 1;
    int bid = blockIdx.x;
    int m0 = (bid & (MT-1)) * 128, n0 = (bid >> 6) * 128;

    f32x16 acc[2][2];
    #pragma unroll
    for (int i=0;i<2;i++)
        #pragma unroll
        for (int j=0;j<2;j++)
            #pragma unroll
            for (int r=0;r<16;r++) acc[i][j][r] = 0.f;

    int lr  = lane >> 3;        // row within 8-row group
    int lch = lane & 7;         // destination LDS chunk
    const ushort_t* gA = A  + (size_t)(m0 + wave*32 + lr)*K + (lch ^ lr)*8;
    const ushort_t* gB = Bt + (size_t)(n0 + wave*32 + lr)*K + (lch ^ lr)*8;
    ushort_t* lA = &As[(wave*32)*64];
    ushort_t* lB = &Bs[(wave*32)*64];
    int sx = lane & 7;          // fragment-read swizzle (row&7 == lane&7)

    for (int k0 = 0; k0 < K; k0 += 64){
        #pragma unroll
        for (int i = 0; i < 4; ++i){
            gload16(gA + (size_t)(i*8)*K + k0, lA + i*8*64);
            gload16(gB + (size_t)(i*8)*K + k0, lB + i*8*64);
        }
        __syncthreads();
        #pragma unroll
        for (int s = 0; s < 4; ++s){
            int ch = ((s<<1) | half) ^ sx;
            bf16x8 af[2], bfr[2];
            #pragma unroll
            for (int i=0;i<2;i++) af[i]  = *(const bf16x8*)&As[(wm*64 + i*32 + l31)*64 + ch*8];
            #pragma unroll
            for (int j=0;j<2;j++) bfr[j] = *(const bf16x8*)&Bs[(wn*64 + j*32 + l31)*64 + ch*8];
            #pragma unroll
            for (int i=0;i<2;i++)
                #pragma unroll
                for (int j=0;j<2;j++)
                    acc[i][j] = __builtin_amdgcn_mfma_f32_32x32x16_bf16(af[i], bfr[j], acc[i][j], 0,0,0);
        }
        __syncthreads();
    }

    // C/D layout (32x32): col = lane&31, row = (reg&3) + 8*(reg>>2) + 4*(lane>>5)
    int rowoff = 4*half;
    #pragma unroll
    for (int i=0;i<2;i++){
        #pragma unroll
        for (int j=0;j<2;j++){
            int n = n0 + wn*64 + j*32 + l31;
            #pragma unroll
            for (int reg=0; reg<16; ++reg){
                int m = m0 + wm*64 + i*32 + (reg&3) + 8*(reg>>2) + rowoff;
                float v = acc[i][j][reg];
                size_t idx = (size_t)m*N + n;
                if (MODE == 0){
                    ((ushort_t*)out)[idx] = f2bf(v);
                } else if (MODE == 1){
                    v += bias[n] + resid[idx];
                    ((float*)out)[idx] = v;
                } else if (MODE == 2){
                    v += bias[n];
                    ((ushort_t*)out)[idx] = f2bf(gelu_f(v));
                } else {
                    v += bias[n] + resid[idx];
                    ((float*)out)[idx] = v;
                }
            }
        }
    }
}

// ---------------- Flash attention (causal), D=64, KV tile = 64, paired q-tiles ----------------
__global__ __launch_bounds__(256) void attn_kernel(const ushort_t* __restrict__ qkv,
                                                   ushort_t* __restrict__ attn_out){
    __shared__ ushort_t Qs[128][72];
    __shared__ ushort_t Ks[64][72];
    __shared__ ushort_t Vts[64][72];   // V transposed + XOR-swizzled
    __shared__ ushort_t Ps[128][72];

    int tid = threadIdx.x;
    int lane = tid & 63, wave = tid >> 6;
    int quad = lane >> 4, l15 = lane & 15;
    int pair = blockIdx.x;         // 0..3
    int bh = blockIdx.y;           // 0..127
    int b = bh >> 4, h = bh & 15;
    size_t tb = (size_t)b * SEQ;

    int tr = tid >> 3;             // 0..31
    int tc = (tid & 7) * 8;        // 0..56
    int sw_w = tid & 7;            // V-write swizzle

    for (int t = 0; t < 2; ++t){
        int qi = t ? (7 - pair) : pair;

        #pragma unroll
        for (int p = 0; p < 4; ++p){
            int r = tr + p*32;
            size_t tok = tb + qi*128 + r;
            *(bf16x8*)&Qs[r][tc] = *(const bf16x8*)(qkv + tok*3072 + h*64 + tc);
        }

        f32x4 o_acc[2][4];
        #pragma unroll
        for (int mt=0;mt<2;mt++)
            #pragma unroll
            for (int nt=0;nt<4;nt++) o_acc[mt][nt] = (f32x4){0.f,0.f,0.f,0.f};
        float m_st[2][4], l_st[2][4];
        #pragma unroll
        for (int mt=0;mt<2;mt++)
            #pragma unroll
            for (int r=0;r<4;r++){ m_st[mt][r] = -1e30f; l_st[mt][r] = 0.f; }

        int nj = 2*qi + 2;
        for (int j = 0; j < nj; ++j){
            #pragma unroll
            for (int p = 0; p < 2; ++p){
                int r = tr + p*32;
                size_t tok = tb + j*64 + r;
                *(bf16x8*)&Ks[r][tc] = *(const bf16x8*)(qkv + tok*3072 + 1024 + h*64 + tc);
                bf16x8 vv = *(const bf16x8*)(qkv + tok*3072 + 2048 + h*64 + tc);
                int kcol = r ^ (sw_w << 3);
                #pragma unroll
                for (int c = 0; c < 8; ++c) Vts[tc + c][kcol] = (ushort_t)vv[c];
            }
            __syncthreads();

            f32x4 s_acc[2][4];
            #pragma unroll
            for (int mt=0;mt<2;mt++)
                #pragma unroll
                for (int nt=0;nt<4;nt++) s_acc[mt][nt] = (f32x4){0.f,0.f,0.f,0.f};
            #pragma unroll
            for (int kf = 0; kf < 2; ++kf){
                bf16x8 aq[2], bk[4];
                #pragma unroll
                for (int mt=0;mt<2;mt++) aq[mt] = *(const bf16x8*)&Qs[wave*32 + mt*16 + l15][kf*32 + quad*8];
                #pragma unroll
                for (int nt=0;nt<4;nt++) bk[nt] = *(const bf16x8*)&Ks[nt*16 + l15][kf*32 + quad*8];
                #pragma unroll
                for (int mt=0;mt<2;mt++)
                    #pragma unroll
                    for (int nt=0;nt<4;nt++)
                        s_acc[mt][nt] = __builtin_amdgcn_mfma_f32_16x16x32_bf16(aq[mt], bk[nt], s_acc[mt][nt], 0,0,0);
            }

            bool need_mask = (j >= 2*qi);
            #pragma unroll
            for (int mt=0;mt<2;mt++)
                #pragma unroll
                for (int nt=0;nt<4;nt++)
                    #pragma unroll
                    for (int r=0;r<4;r++){
                        float s = s_acc[mt][nt][r] * 0.125f;
                        if (need_mask){
                            int qg = qi*128 + wave*32 + mt*16 + quad*4 + r;
                            int kg = j*64 + nt*16 + l15;
                            if (kg > qg) s = -1e30f;
                        }
                        s_acc[mt][nt][r] = s;
                    }

            #pragma unroll
            for (int mt=0;mt<2;mt++){
                #pragma unroll
                for (int r=0;r<4;r++){
                    float rm = s_acc[mt][0][r];
                    #pragma unroll
                    for (int nt=1;nt<4;nt++) rm = fmaxf(rm, s_acc[mt][nt][r]);
                    rm = fmaxf(rm, __shfl_xor(rm, 1));
                    rm = fmaxf(rm, __shfl_xor(rm, 2));
                    rm = fmaxf(rm, __shfl_xor(rm, 4));
                    rm = fmaxf(rm, __shfl_xor(rm, 8));
                    float mnew = fmaxf(m_st[mt][r], rm);
                    float alpha = __expf(m_st[mt][r] - mnew);
                    float rsum = 0.f;
                    #pragma unroll
                    for (int nt=0;nt<4;nt++){
                        float p = __expf(s_acc[mt][nt][r] - mnew);
                        s_acc[mt][nt][r] = p;
                        rsum += p;
                    }
                    rsum += __shfl_xor(rsum, 1);
                    rsum += __shfl_xor(rsum, 2);
                    rsum += __shfl_xor(rsum, 4);
                    rsum += __shfl_xor(rsum, 8);
                    l_st[mt][r] = l_st[mt][r]*alpha + rsum;
                    m_st[mt][r] = mnew;
                    #pragma unroll
                    for (int nt=0;nt<4;nt++) o_acc[mt][nt][r] *= alpha;
                }
            }

            #pragma unroll
            for (int mt=0;mt<2;mt++)
                #pragma unroll
                for (int nt=0;nt<4;nt++)
                    #pragma unroll
                    for (int r=0;r<4;r++)
                        Ps[wave*32 + mt*16 + quad*4 + r][nt*16 + l15] = f2bf(s_acc[mt][nt][r]);

            #pragma unroll
            for (int kf = 0; kf < 2; ++kf){
                bf16x8 ap[2], bv[4];
                #pragma unroll
                for (int mt=0;mt<2;mt++) ap[mt] = *(const bf16x8*)&Ps[wave*32 + mt*16 + l15][kf*32 + quad*8];
                #pragma unroll
                for (int nt=0;nt<4;nt++){
                    int d = nt*16 + l15;
                    int col = (kf*32 + quad*8) ^ (((d >> 3) & 7) << 3);
                    bv[nt] = *(const bf16x8*)&Vts[d][col];
                }
                #pragma unroll
                for (int mt=0;mt<2;mt++)
                    #pragma unroll
                    for (int nt=0;nt<4;nt++)
                        o_acc[mt][nt] = __builtin_amdgcn_mfma_f32_16x16x32_bf16(ap[mt], bv[nt], o_acc[mt][nt], 0,0,0);
            }
            __syncthreads();
        }

        #pragma unroll
        for (int mt=0;mt<2;mt++)
            #pragma unroll
            for (int r=0;r<4;r++){
                float inv = 1.0f / l_st[mt][r];
                size_t tok = tb + qi*128 + wave*32 + mt*16 + quad*4 + r;
                #pragma unroll
                for (int nt=0;nt<4;nt++)
                    attn_out[tok*EMB + h*64 + nt*16 + l15] = f2bf(o_acc[mt][nt][r] * inv);
            }
    }
}

extern "C" void kernel_launch(void* const* d_in, const int* in_sizes, int n_in,
                              void* d_out, int out_size, void* d_ws, size_t ws_size,
                              hipStream_t stream){
    const float* x      = (const float*)d_in[0];
    const float* ln1_g  = (const float*)d_in[1];
    const float* ln1_b  = (const float*)d_in[2];
    const float* wq     = (const float*)d_in[3];
    const float* wk     = (const float*)d_in[4];
    const float* wv     = (const float*)d_in[5];
    const float* w_proj = (const float*)d_in[6];
    const float* b_proj = (const float*)d_in[7];
    const float* ln2_g  = (const float*)d_in[8];
    const float* ln2_b  = (const float*)d_in[9];
    const float* w1     = (const float*)d_in[10];
    const float* b1     = (const float*)d_in[11];
    const float* w2     = (const float*)d_in[12];
    const float* b2     = (const float*)d_in[13];
    float* outp = (float*)d_out;

    char* ws = (char*)d_ws;
    size_t off = 0;
    auto alloc = [&](size_t bytes)->char*{ char* p = ws + off; off += (bytes + 255) & ~255ULL; return p; };
    ushort_t* wqkv_t = (ushort_t*)alloc((size_t)3072*1024*2);
    ushort_t* wproj_t= (ushort_t*)alloc((size_t)1024*1024*2);
    ushort_t* w1_t   = (ushort_t*)alloc((size_t)4096*1024*2);
    ushort_t* w2_t   = (ushort_t*)alloc((size_t)1024*4096*2);
    ushort_t* qkv    = (ushort_t*)alloc((size_t)ROWS*3072*2);
    ushort_t* hbuf   = (ushort_t*)alloc((size_t)ROWS*1024*2);
    float*    out32  = (float*)  alloc((size_t)ROWS*1024*4);
    ushort_t* mid    = (ushort_t*)alloc((size_t)ROWS*4096*2);
    ushort_t* h1 = hbuf;
    ushort_t* attn = hbuf;   // h1 dead after qkv GEMM
    ushort_t* h2 = qkv;      // qkv dead after attention

    dim3 blk(256);
    transpose_w<<<dim3(32,32),  blk, 0, stream>>>(wq,     wqkv_t,               1024, 1024);
    transpose_w<<<dim3(32,32),  blk, 0, stream>>>(wk,     wqkv_t + 1024*1024,   1024, 1024);
    transpose_w<<<dim3(32,32),  blk, 0, stream>>>(wv,     wqkv_t + 2*1024*1024, 1024, 1024);
    transpose_w<<<dim3(32,32),  blk, 0, stream>>>(w_proj, wproj_t,              1024, 1024);
    transpose_w<<<dim3(128,32), blk, 0, stream>>>(w1,     w1_t,                 1024, 4096);
    transpose_w<<<dim3(32,128), blk, 0, stream>>>(w2,     w2_t,                 4096, 1024);

    ln_kernel<<<ROWS, blk, 0, stream>>>(x, ln1_g, ln1_b, h1);
    gemm_kernel<0><<<dim3(MT*(3072/128)), blk, 0, stream>>>(h1, wqkv_t, nullptr, nullptr, qkv, ROWS, 3072, 1024);
    attn_kernel<<<dim3(4,128), blk, 0, stream>>>(qkv, attn);
    gemm_kernel<1><<<dim3(MT*(1024/128)), blk, 0, stream>>>(attn, wproj_t, b_proj, x, out32, ROWS, 1024, 1024);
    ln_kernel<<<ROWS, blk, 0, stream>>>(out32, ln2_g, ln2_b, h2);
    gemm_kernel<2><<<dim3(MT*(4096/128)), blk, 0, stream>>>(h2, w1_t, b1, nullptr, mid, ROWS, 4096, 1024);
    gemm_kernel<3><<<dim3(MT*(1024/128)), blk, 0, stream>>>(mid, w2_t, b2, out32, outp, ROWS, 1024, 4096);
}

// Round 7
// 463.482 us; speedup vs baseline: 1.1781x; 1.0561x over previous
//
#include <hip/hip_runtime.h>
#include <hip/hip_bf16.h>

#define EMB 1024
#define NH 16
#define HD 64
#define BATCH 8
#define SEQ 1024
#define ROWS (BATCH*SEQ)   // 8192
#define MT (ROWS/128)      // 64 m-tiles

typedef unsigned short ushort_t;
typedef __attribute__((ext_vector_type(8))) short bf16x8;
typedef __attribute__((ext_vector_type(4))) float f32x4;
typedef __attribute__((ext_vector_type(16))) float f32x16;

__device__ __forceinline__ float bf2f(ushort_t u){
    union { unsigned int i; float f; } v; v.i = ((unsigned int)u) << 16; return v.f;
}
__device__ __forceinline__ ushort_t f2bf(float f){
    unsigned int u = __float_as_uint(f);
    unsigned int r = (u + 0x7FFFu + ((u >> 16) & 1u)) >> 16;
    return (ushort_t)r;
}
__device__ __forceinline__ void gload16(const ushort_t* g, ushort_t* l){
    __builtin_amdgcn_global_load_lds(
        (const __attribute__((address_space(1))) void*)g,
        (__attribute__((address_space(3))) void*)l,
        16, 0, 0);
}
// exact-erf GELU via A&S 7.1.26 (|err| < 1.5e-7)
__device__ __forceinline__ float gelu_f(float v){
    float x = fabsf(v) * 0.70710678118654752f;
    float t = __builtin_amdgcn_rcpf(1.0f + 0.3275911f * x);
    float poly = t*(0.254829592f + t*(-0.284496736f + t*(1.421413741f + t*(-1.453152027f + t*1.061405429f))));
    float erfa = 1.0f - poly * __expf(-x*x);
    float erfv = (v >= 0.f) ? erfa : -erfa;
    return 0.5f * v * (1.0f + erfv);
}

// ---------------- weight transpose + convert (f32 [K][N] -> bf16 [N][K]) ----------------
__global__ __launch_bounds__(256) void transpose_w(const float* __restrict__ in,
                                                   ushort_t* __restrict__ out,
                                                   int K, int N){
    __shared__ ushort_t t[32][33];
    int tx = threadIdx.x & 31, ty = threadIdx.x >> 5;
    int bx = blockIdx.x, by = blockIdx.y;
    #pragma unroll
    for (int r = 0; r < 4; ++r)
        t[ty + r*8][tx] = f2bf(in[(size_t)(by*32 + ty + r*8) * N + bx*32 + tx]);
    __syncthreads();
    #pragma unroll
    for (int r = 0; r < 4; ++r)
        out[(size_t)(bx*32 + ty + r*8) * K + by*32 + tx] = t[tx][ty + r*8];
}

// ---------------- LayerNorm (row = 1024), f32 in -> bf16 out ----------------
__global__ __launch_bounds__(256) void ln_kernel(const float* __restrict__ xin,
                                                 const float* __restrict__ g,
                                                 const float* __restrict__ bia,
                                                 ushort_t* __restrict__ out){
    int row = blockIdx.x;
    int tid = threadIdx.x;
    const float* x = xin + (size_t)row * EMB;
    float4 f = *(const float4*)(x + tid*4);
    float v[4] = {f.x, f.y, f.z, f.w};
    float s = v[0]+v[1]+v[2]+v[3];
    float q = v[0]*v[0]+v[1]*v[1]+v[2]*v[2]+v[3]*v[3];
    #pragma unroll
    for (int o = 32; o > 0; o >>= 1){ s += __shfl_down(s, o); q += __shfl_down(q, o); }
    __shared__ float ss[4], qq[4];
    __shared__ float mu_s, sc_s;
    int wave = tid >> 6, lane = tid & 63;
    if (lane == 0){ ss[wave] = s; qq[wave] = q; }
    __syncthreads();
    if (tid == 0){
        float S = ss[0]+ss[1]+ss[2]+ss[3];
        float Q = qq[0]+qq[1]+qq[2]+qq[3];
        float mu = S * (1.0f/EMB);
        float var = Q * (1.0f/EMB) - mu*mu;
        mu_s = mu; sc_s = rsqrtf(var + 1e-5f);
    }
    __syncthreads();
    float mu = mu_s, sc = sc_s;
    float4 gu = *(const float4*)(g + tid*4);
    float4 bu = *(const float4*)(bia + tid*4);
    ushort4 o4;
    o4.x = f2bf((v[0]-mu)*sc*gu.x + bu.x);
    o4.y = f2bf((v[1]-mu)*sc*gu.y + bu.y);
    o4.z = f2bf((v[2]-mu)*sc*gu.z + bu.z);
    o4.w = f2bf((v[3]-mu)*sc*gu.w + bu.w);
    *(ushort4*)(out + (size_t)row*EMB + tid*4) = o4;
}

// ---------------- GEMM: 128x128 tile, 32x32x16 MFMA, XOR-swizzled LDS ----------------
// 1-D grid, mt = bid & 63 / nt = bid >> 6  => same-m blocks share an XCD (L2 A-reuse).
// LDS chunk c (16B) of row r holds global chunk c ^ (r&7) -> conflict-light b128 reads.
// MODE 0: plain -> bf16 | 1: +bias+resid -> f32 | 2: +bias+GELU -> bf16 | 3: +bias+resid -> f32
template<int MODE>
__global__ __launch_bounds__(256) void gemm_kernel(const ushort_t* __restrict__ A,
                                                   const ushort_t* __restrict__ Bt,
                                                   const float* __restrict__ bias,
                                                   const float* __restrict__ resid,
                                                   void* __restrict__ out,
                                                   int M, int N, int K){
    __shared__ ushort_t As[128*64];
    __shared__ ushort_t Bs[128*64];
    int tid = threadIdx.x;
    int lane = tid & 63, wave = tid >> 6;
    int l31 = lane & 31, half = lane >> 5;
    int wm = wave >> 1, wn = wave & 1;
    int bid = blockIdx.x;
    int m0 = (bid & (MT-1)) * 128, n0 = (bid >> 6) * 128;

    f32x16 acc[2][2];
    #pragma unroll
    for (int i=0;i<2;i++)
        #pragma unroll
        for (int j=0;j<2;j++)
            #pragma unroll
            for (int r=0;r<16;r++) acc[i][j][r] = 0.f;

    int lr  = lane >> 3;        // row within 8-row group
    int lch = lane & 7;         // destination LDS chunk
    const ushort_t* gA = A  + (size_t)(m0 + wave*32 + lr)*K + (lch ^ lr)*8;
    const ushort_t* gB = Bt + (size_t)(n0 + wave*32 + lr)*K + (lch ^ lr)*8;
    ushort_t* lA = &As[(wave*32)*64];
    ushort_t* lB = &Bs[(wave*32)*64];
    int sx = lane & 7;          // fragment-read swizzle (row&7 == lane&7)

    for (int k0 = 0; k0 < K; k0 += 64){
        #pragma unroll
        for (int i = 0; i < 4; ++i){
            gload16(gA + (size_t)(i*8)*K + k0, lA + i*8*64);
            gload16(gB + (size_t)(i*8)*K + k0, lB + i*8*64);
        }
        __syncthreads();
        #pragma unroll
        for (int s = 0; s < 4; ++s){
            int ch = ((s<<1) | half) ^ sx;
            bf16x8 af[2], bfr[2];
            #pragma unroll
            for (int i=0;i<2;i++) af[i]  = *(const bf16x8*)&As[(wm*64 + i*32 + l31)*64 + ch*8];
            #pragma unroll
            for (int j=0;j<2;j++) bfr[j] = *(const bf16x8*)&Bs[(wn*64 + j*32 + l31)*64 + ch*8];
            #pragma unroll
            for (int i=0;i<2;i++)
                #pragma unroll
                for (int j=0;j<2;j++)
                    acc[i][j] = __builtin_amdgcn_mfma_f32_32x32x16_bf16(af[i], bfr[j], acc[i][j], 0,0,0);
        }
        __syncthreads();
    }

    // C/D layout (32x32): col = lane&31, row = (reg&3) + 8*(reg>>2) + 4*(lane>>5)
    int rowoff = 4*half;
    #pragma unroll
    for (int i=0;i<2;i++){
        #pragma unroll
        for (int j=0;j<2;j++){
            int n = n0 + wn*64 + j*32 + l31;
            #pragma unroll
            for (int reg=0; reg<16; ++reg){
                int m = m0 + wm*64 + i*32 + (reg&3) + 8*(reg>>2) + rowoff;
                float v = acc[i][j][reg];
                size_t idx = (size_t)m*N + n;
                if (MODE == 0){
                    ((ushort_t*)out)[idx] = f2bf(v);
                } else if (MODE == 1){
                    v += bias[n] + resid[idx];
                    ((float*)out)[idx] = v;
                } else if (MODE == 2){
                    v += bias[n];
                    ((ushort_t*)out)[idx] = f2bf(gelu_f(v));
                } else {
                    v += bias[n] + resid[idx];
                    ((float*)out)[idx] = v;
                }
            }
        }
    }
}

// ---------------- Flash attention (causal), S^T formulation ----------------
// S^T = K·Q^T so the MFMA C-layout holds 16 KV-values per q-column IN-LANE:
// softmax = in-lane reduce + 2 shuffles (xor16/32 across quads); P^T packs as
// ds_write_b64; O^T = V^T·P^T gives 8B-packed global stores.
__global__ __launch_bounds__(256) void attn_kernel(const ushort_t* __restrict__ qkv,
                                                   ushort_t* __restrict__ attn_out){
    __shared__ ushort_t Qs[128*64];    // [q][d], gload chunk-swizzled
    __shared__ ushort_t Ks[64*64];     // [kv][d], gload chunk-swizzled
    __shared__ ushort_t Vts[64][72];   // V^T [d][kv], write-swizzled
    __shared__ ushort_t Ps[128*64];    // P [q][kv], XOR-slotted

    int tid = threadIdx.x;
    int lane = tid & 63, wave = tid >> 6;
    int quad = lane >> 4, l15 = lane & 15;
    int pair = blockIdx.x;         // 0..3
    int bh = blockIdx.y;           // 0..127
    int b = bh >> 4, h = bh & 15;
    size_t tb = (size_t)b * SEQ;

    int lr = lane >> 3, lch = lane & 7;   // gload lane decomposition
    int tr = tid >> 3;                    // V staging: rows 0..31
    int tc = (tid & 7) * 8;
    int sw_w = tid & 7;
    int sx = l15 & 7;                     // fragment-read chunk swizzle

    for (int t = 0; t < 2; ++t){
        int qi = t ? (7 - pair) : pair;

        // stage Q [128][64] via global_load_lds (chunk c of row r at slot c^(r&7))
        {
            const ushort_t* gq = qkv + (size_t)(tb + qi*128 + wave*32 + lr)*3072 + h*64 + (lch^lr)*8;
            ushort_t* lq = &Qs[(wave*32)*64];
            #pragma unroll
            for (int p = 0; p < 4; ++p)
                gload16(gq + (size_t)(p*8)*3072, lq + p*8*64);
        }

        f32x4 o_acc[4][2];
        #pragma unroll
        for (int i=0;i<4;i++)
            #pragma unroll
            for (int j=0;j<2;j++) o_acc[i][j] = (f32x4){0.f,0.f,0.f,0.f};
        float m_st[2] = {-1e30f, -1e30f};
        float l_st[2] = {0.f, 0.f};

        int nj = 2*qi + 2;
        for (int j = 0; j < nj; ++j){
            // stage K [64][64] via gload; V^T scalar transposed+swizzled
            {
                const ushort_t* gk = qkv + (size_t)(tb + j*64 + wave*16 + lr)*3072 + 1024 + h*64 + (lch^lr)*8;
                ushort_t* lk = &Ks[(wave*16)*64];
                gload16(gk, lk);
                gload16(gk + (size_t)8*3072, lk + 8*64);
            }
            #pragma unroll
            for (int p = 0; p < 2; ++p){
                int r = tr + p*32;
                bf16x8 vv = *(const bf16x8*)(qkv + (size_t)(tb + j*64 + r)*3072 + 2048 + h*64 + tc);
                int kcol = r ^ (sw_w << 3);
                #pragma unroll
                for (int c = 0; c < 8; ++c) Vts[tc + c][kcol] = (ushort_t)vv[c];
            }
            __syncthreads();

            // S^T[kv 64][q 32/wave] = K·Q^T
            f32x4 st[4][2];
            #pragma unroll
            for (int mt=0;mt<4;mt++)
                #pragma unroll
                for (int nt=0;nt<2;nt++) st[mt][nt] = (f32x4){0.f,0.f,0.f,0.f};
            #pragma unroll
            for (int kf = 0; kf < 2; ++kf){
                int ch = (kf*4 + quad) ^ sx;
                bf16x8 ak[4], bq[2];
                #pragma unroll
                for (int mt=0;mt<4;mt++) ak[mt] = *(const bf16x8*)&Ks[(mt*16 + l15)*64 + ch*8];
                #pragma unroll
                for (int nt=0;nt<2;nt++) bq[nt] = *(const bf16x8*)&Qs[(wave*32 + nt*16 + l15)*64 + ch*8];
                #pragma unroll
                for (int mt=0;mt<4;mt++)
                    #pragma unroll
                    for (int nt=0;nt<2;nt++)
                        st[mt][nt] = __builtin_amdgcn_mfma_f32_16x16x32_bf16(ak[mt], bq[nt], st[mt][nt], 0,0,0);
            }

            // scale + causal mask (kv on M axis now)
            bool need_mask = (j >= 2*qi);
            #pragma unroll
            for (int mt=0;mt<4;mt++)
                #pragma unroll
                for (int nt=0;nt<2;nt++)
                    #pragma unroll
                    for (int r=0;r<4;r++){
                        float s = st[mt][nt][r] * 0.125f;
                        if (need_mask){
                            int kg = j*64 + mt*16 + quad*4 + r;
                            int qg = qi*128 + wave*32 + nt*16 + l15;
                            if (kg > qg) s = -1e30f;
                        }
                        st[mt][nt][r] = s;
                    }

            // online softmax per q-column (16 kv in-lane + cross-quad xor16/32)
            #pragma unroll
            for (int nt = 0; nt < 2; ++nt){
                float mx = st[0][nt][0];
                #pragma unroll
                for (int mt=0;mt<4;mt++)
                    #pragma unroll
                    for (int r=0;r<4;r++) mx = fmaxf(mx, st[mt][nt][r]);
                mx = fmaxf(mx, __shfl_xor(mx, 16));
                mx = fmaxf(mx, __shfl_xor(mx, 32));
                float mnew = fmaxf(m_st[nt], mx);
                float al = __expf(m_st[nt] - mnew);
                float ps = 0.f;
                #pragma unroll
                for (int mt=0;mt<4;mt++)
                    #pragma unroll
                    for (int r=0;r<4;r++){
                        float p = __expf(st[mt][nt][r] - mnew);
                        st[mt][nt][r] = p;
                        ps += p;
                    }
                ps += __shfl_xor(ps, 16);
                ps += __shfl_xor(ps, 32);
                l_st[nt] = l_st[nt]*al + ps;
                m_st[nt] = mnew;
                #pragma unroll
                for (int mtd=0;mtd<4;mtd++)
                    #pragma unroll
                    for (int r=0;r<4;r++) o_acc[mtd][nt][r] *= al;
                // pack P^T: 4 consecutive kv -> b64, slot = kvchunk ^ (q&7)
                #pragma unroll
                for (int mt=0;mt<4;mt++){
                    int slot = (mt*2 + (quad>>1)) ^ sx;
                    ushort4 pk;
                    pk.x = f2bf(st[mt][nt][0]); pk.y = f2bf(st[mt][nt][1]);
                    pk.z = f2bf(st[mt][nt][2]); pk.w = f2bf(st[mt][nt][3]);
                    *(ushort4*)&Ps[(wave*32 + nt*16 + l15)*64 + slot*8 + (quad&1)*4] = pk;
                }
            }

            // O^T[d 64][q 32/wave] += V^T·P^T
            #pragma unroll
            for (int kf = 0; kf < 2; ++kf){
                bf16x8 av[4], bp[2];
                #pragma unroll
                for (int mtd=0;mtd<4;mtd++){
                    int d = mtd*16 + l15;
                    int col = (kf*32 + quad*8) ^ (((d >> 3) & 7) << 3);
                    av[mtd] = *(const bf16x8*)&Vts[d][col];
                }
                #pragma unroll
                for (int nt=0;nt<2;nt++){
                    int ch = (kf*4 + quad) ^ sx;
                    bp[nt] = *(const bf16x8*)&Ps[(wave*32 + nt*16 + l15)*64 + ch*8];
                }
                #pragma unroll
                for (int mtd=0;mtd<4;mtd++)
                    #pragma unroll
                    for (int nt=0;nt<2;nt++)
                        o_acc[mtd][nt] = __builtin_amdgcn_mfma_f32_16x16x32_bf16(av[mtd], bp[nt], o_acc[mtd][nt], 0,0,0);
            }
            __syncthreads();
        }

        // epilogue: O^T regs = 4 consecutive d per q -> 8B packed stores
        #pragma unroll
        for (int nt = 0; nt < 2; ++nt){
            float inv = 1.0f / l_st[nt];
            size_t tok = tb + qi*128 + wave*32 + nt*16 + l15;
            #pragma unroll
            for (int mtd = 0; mtd < 4; ++mtd){
                ushort4 ok;
                ok.x = f2bf(o_acc[mtd][nt][0]*inv); ok.y = f2bf(o_acc[mtd][nt][1]*inv);
                ok.z = f2bf(o_acc[mtd][nt][2]*inv); ok.w = f2bf(o_acc[mtd][nt][3]*inv);
                *(ushort4*)(attn_out + tok*EMB + h*64 + mtd*16 + quad*4) = ok;
            }
        }
    }
}

extern "C" void kernel_launch(void* const* d_in, const int* in_sizes, int n_in,
                              void* d_out, int out_size, void* d_ws, size_t ws_size,
                              hipStream_t stream){
    const float* x      = (const float*)d_in[0];
    const float* ln1_g  = (const float*)d_in[1];
    const float* ln1_b  = (const float*)d_in[2];
    const float* wq     = (const float*)d_in[3];
    const float* wk     = (const float*)d_in[4];
    const float* wv     = (const float*)d_in[5];
    const float* w_proj = (const float*)d_in[6];
    const float* b_proj = (const float*)d_in[7];
    const float* ln2_g  = (const float*)d_in[8];
    const float* ln2_b  = (const float*)d_in[9];
    const float* w1     = (const float*)d_in[10];
    const float* b1     = (const float*)d_in[11];
    const float* w2     = (const float*)d_in[12];
    const float* b2     = (const float*)d_in[13];
    float* outp = (float*)d_out;

    char* ws = (char*)d_ws;
    size_t off = 0;
    auto alloc = [&](size_t bytes)->char*{ char* p = ws + off; off += (bytes + 255) & ~255ULL; return p; };
    ushort_t* wqkv_t = (ushort_t*)alloc((size_t)3072*1024*2);
    ushort_t* wproj_t= (ushort_t*)alloc((size_t)1024*1024*2);
    ushort_t* w1_t   = (ushort_t*)alloc((size_t)4096*1024*2);
    ushort_t* w2_t   = (ushort_t*)alloc((size_t)1024*4096*2);
    ushort_t* qkv    = (ushort_t*)alloc((size_t)ROWS*3072*2);
    ushort_t* hbuf   = (ushort_t*)alloc((size_t)ROWS*1024*2);
    float*    out32  = (float*)  alloc((size_t)ROWS*1024*4);
    ushort_t* mid    = (ushort_t*)alloc((size_t)ROWS*4096*2);
    ushort_t* h1 = hbuf;
    ushort_t* attn = hbuf;   // h1 dead after qkv GEMM
    ushort_t* h2 = qkv;      // qkv dead after attention

    dim3 blk(256);
    transpose_w<<<dim3(32,32),  blk, 0, stream>>>(wq,     wqkv_t,               1024, 1024);
    transpose_w<<<dim3(32,32),  blk, 0, stream>>>(wk,     wqkv_t + 1024*1024,   1024, 1024);
    transpose_w<<<dim3(32,32),  blk, 0, stream>>>(wv,     wqkv_t + 2*1024*1024, 1024, 1024);
    transpose_w<<<dim3(32,32),  blk, 0, stream>>>(w_proj, wproj_t,              1024, 1024);
    transpose_w<<<dim3(128,32), blk, 0, stream>>>(w1,     w1_t,                 1024, 4096);
    transpose_w<<<dim3(32,128), blk, 0, stream>>>(w2,     w2_t,                 4096, 1024);

    ln_kernel<<<ROWS, blk, 0, stream>>>(x, ln1_g, ln1_b, h1);
    gemm_kernel<0><<<dim3(MT*(3072/128)), blk, 0, stream>>>(h1, wqkv_t, nullptr, nullptr, qkv, ROWS, 3072, 1024);
    attn_kernel<<<dim3(4,128), blk, 0, stream>>>(qkv, attn);
    gemm_kernel<1><<<dim3(MT*(1024/128)), blk, 0, stream>>>(attn, wproj_t, b_proj, x, out32, ROWS, 1024, 1024);
    ln_kernel<<<ROWS, blk, 0, stream>>>(out32, ln2_g, ln2_b, h2);
    gemm_kernel<2><<<dim3(MT*(4096/128)), blk, 0, stream>>>(h2, w1_t, b1, nullptr, mid, ROWS, 4096, 1024);
    gemm_kernel<3><<<dim3(MT*(1024/128)), blk, 0, stream>>>(mid, w2_t, b2, out32, outp, ROWS, 1024, 4096);
}

// Round 8
// 462.471 us; speedup vs baseline: 1.1806x; 1.0022x over previous
//
#include <hip/hip_runtime.h>
#include <hip/hip_bf16.h>

#define EMB 1024
#define NH 16
#define HD 64
#define BATCH 8
#define SEQ 1024
#define ROWS (BATCH*SEQ)   // 8192
#define MT (ROWS/128)      // 64 m-tiles

typedef unsigned short ushort_t;
typedef __attribute__((ext_vector_type(8))) short bf16x8;
typedef __attribute__((ext_vector_type(4))) float f32x4;
typedef __attribute__((ext_vector_type(16))) float f32x16;

__device__ __forceinline__ float bf2f(ushort_t u){
    union { unsigned int i; float f; } v; v.i = ((unsigned int)u) << 16; return v.f;
}
__device__ __forceinline__ ushort_t f2bf(float f){
    unsigned int u = __float_as_uint(f);
    unsigned int r = (u + 0x7FFFu + ((u >> 16) & 1u)) >> 16;
    return (ushort_t)r;
}
__device__ __forceinline__ void gload16(const ushort_t* g, ushort_t* l){
    __builtin_amdgcn_global_load_lds(
        (const __attribute__((address_space(1))) void*)g,
        (__attribute__((address_space(3))) void*)l,
        16, 0, 0);
}
// exact-erf GELU via A&S 7.1.26 (|err| < 1.5e-7)
__device__ __forceinline__ float gelu_f(float v){
    float x = fabsf(v) * 0.70710678118654752f;
    float t = __builtin_amdgcn_rcpf(1.0f + 0.3275911f * x);
    float poly = t*(0.254829592f + t*(-0.284496736f + t*(1.421413741f + t*(-1.453152027f + t*1.061405429f))));
    float erfa = 1.0f - poly * __expf(-x*x);
    float erfv = (v >= 0.f) ? erfa : -erfa;
    return 0.5f * v * (1.0f + erfv);
}

// ---------------- fused prep: LN1 (blocks 0..8191) + all 6 weight transposes ----------------
__global__ __launch_bounds__(256) void prep_kernel(const float* __restrict__ x,
                                                   const float* __restrict__ ln1_g,
                                                   const float* __restrict__ ln1_b,
                                                   ushort_t* __restrict__ h1,
                                                   const float* __restrict__ wq,
                                                   const float* __restrict__ wk,
                                                   const float* __restrict__ wv,
                                                   const float* __restrict__ w_proj,
                                                   const float* __restrict__ w1,
                                                   const float* __restrict__ w2,
                                                   ushort_t* __restrict__ wqkv_t,
                                                   ushort_t* __restrict__ wproj_t,
                                                   ushort_t* __restrict__ w1_t,
                                                   ushort_t* __restrict__ w2_t){
    int bid = blockIdx.x;
    int tid = threadIdx.x;
    if (bid < ROWS){
        // ---- LayerNorm row ----
        __shared__ float ss[4], qq[4];
        __shared__ float mu_s, sc_s;
        const float* xr = x + (size_t)bid * EMB;
        float4 f = *(const float4*)(xr + tid*4);
        float v[4] = {f.x, f.y, f.z, f.w};
        float s = v[0]+v[1]+v[2]+v[3];
        float q = v[0]*v[0]+v[1]*v[1]+v[2]*v[2]+v[3]*v[3];
        #pragma unroll
        for (int o = 32; o > 0; o >>= 1){ s += __shfl_down(s, o); q += __shfl_down(q, o); }
        int wave = tid >> 6, lane = tid & 63;
        if (lane == 0){ ss[wave] = s; qq[wave] = q; }
        __syncthreads();
        if (tid == 0){
            float S = ss[0]+ss[1]+ss[2]+ss[3];
            float Q = qq[0]+qq[1]+qq[2]+qq[3];
            float mu = S * (1.0f/EMB);
            float var = Q * (1.0f/EMB) - mu*mu;
            mu_s = mu; sc_s = rsqrtf(var + 1e-5f);
        }
        __syncthreads();
        float mu = mu_s, sc = sc_s;
        float4 gu = *(const float4*)(ln1_g + tid*4);
        float4 bu = *(const float4*)(ln1_b + tid*4);
        ushort4 o4;
        o4.x = f2bf((v[0]-mu)*sc*gu.x + bu.x);
        o4.y = f2bf((v[1]-mu)*sc*gu.y + bu.y);
        o4.z = f2bf((v[2]-mu)*sc*gu.z + bu.z);
        o4.w = f2bf((v[3]-mu)*sc*gu.w + bu.w);
        *(ushort4*)(h1 + (size_t)bid*EMB + tid*4) = o4;
    } else {
        // ---- weight transpose tile (f32 [K][N] -> bf16 [N][K]) ----
        __shared__ ushort_t t[32][33];
        int j = bid - ROWS;
        const float* in; ushort_t* out; int K, N, bx, by;
        if (j < 3072){
            int which = j >> 10, jj = j & 1023;
            in = (which == 0) ? wq : (which == 1) ? wk : wv;
            out = wqkv_t + (size_t)which * 1024 * 1024;
            K = 1024; N = 1024; bx = jj & 31; by = jj >> 5;
        } else if (j < 4096){
            int jj = j - 3072;
            in = w_proj; out = wproj_t; K = 1024; N = 1024; bx = jj & 31; by = jj >> 5;
        } else if (j < 8192){
            int jj = j - 4096;
            in = w1; out = w1_t; K = 1024; N = 4096; bx = jj & 127; by = jj >> 7;
        } else {
            int jj = j - 8192;
            in = w2; out = w2_t; K = 4096; N = 1024; bx = jj & 31; by = jj >> 5;
        }
        int tx = tid & 31, ty = tid >> 5;
        #pragma unroll
        for (int r = 0; r < 4; ++r)
            t[ty + r*8][tx] = f2bf(in[(size_t)(by*32 + ty + r*8) * N + bx*32 + tx]);
        __syncthreads();
        #pragma unroll
        for (int r = 0; r < 4; ++r)
            out[(size_t)(bx*32 + ty + r*8) * K + by*32 + tx] = t[tx][ty + r*8];
    }
}

// ---------------- LayerNorm (row = 1024), f32 in -> bf16 out ----------------
__global__ __launch_bounds__(256) void ln_kernel(const float* __restrict__ xin,
                                                 const float* __restrict__ g,
                                                 const float* __restrict__ bia,
                                                 ushort_t* __restrict__ out){
    int row = blockIdx.x;
    int tid = threadIdx.x;
    const float* x = xin + (size_t)row * EMB;
    float4 f = *(const float4*)(x + tid*4);
    float v[4] = {f.x, f.y, f.z, f.w};
    float s = v[0]+v[1]+v[2]+v[3];
    float q = v[0]*v[0]+v[1]*v[1]+v[2]*v[2]+v[3]*v[3];
    #pragma unroll
    for (int o = 32; o > 0; o >>= 1){ s += __shfl_down(s, o); q += __shfl_down(q, o); }
    __shared__ float ss[4], qq[4];
    __shared__ float mu_s, sc_s;
    int wave = tid >> 6, lane = tid & 63;
    if (lane == 0){ ss[wave] = s; qq[wave] = q; }
    __syncthreads();
    if (tid == 0){
        float S = ss[0]+ss[1]+ss[2]+ss[3];
        float Q = qq[0]+qq[1]+qq[2]+qq[3];
        float mu = S * (1.0f/EMB);
        float var = Q * (1.0f/EMB) - mu*mu;
        mu_s = mu; sc_s = rsqrtf(var + 1e-5f);
    }
    __syncthreads();
    float mu = mu_s, sc = sc_s;
    float4 gu = *(const float4*)(g + tid*4);
    float4 bu = *(const float4*)(bia + tid*4);
    ushort4 o4;
    o4.x = f2bf((v[0]-mu)*sc*gu.x + bu.x);
    o4.y = f2bf((v[1]-mu)*sc*gu.y + bu.y);
    o4.z = f2bf((v[2]-mu)*sc*gu.z + bu.z);
    o4.w = f2bf((v[3]-mu)*sc*gu.w + bu.w);
    *(ushort4*)(out + (size_t)row*EMB + tid*4) = o4;
}

// ---------------- GEMM: 128x128 tile, 32x32x16 MFMA, XOR-swizzled LDS ----------------
// 1-D grid, mt = bid & 63 / nt = bid >> 6  => same-m blocks share an XCD (L2 A-reuse).
// LDS chunk c (16B) of row r holds global chunk c ^ (r&7) -> conflict-light b128 reads.
// MODE 0: plain -> bf16 | 1: +bias+resid -> f32 | 2: +bias+GELU -> bf16 | 3: +bias+resid -> f32
template<int MODE>
__global__ __launch_bounds__(256) void gemm_kernel(const ushort_t* __restrict__ A,
                                                   const ushort_t* __restrict__ Bt,
                                                   const float* __restrict__ bias,
                                                   const float* __restrict__ resid,
                                                   void* __restrict__ out,
                                                   int M, int N, int K){
    __shared__ ushort_t As[128*64];
    __shared__ ushort_t Bs[128*64];
    int tid = threadIdx.x;
    int lane = tid & 63, wave = tid >> 6;
    int l31 = lane & 31, half = lane >> 5;
    int wm = wave >> 1, wn = wave & 1;
    int bid = blockIdx.x;
    int m0 = (bid & (MT-1)) * 128, n0 = (bid >> 6) * 128;

    f32x16 acc[2][2];
    #pragma unroll
    for (int i=0;i<2;i++)
        #pragma unroll
        for (int j=0;j<2;j++)
            #pragma unroll
            for (int r=0;r<16;r++) acc[i][j][r] = 0.f;

    int lr  = lane >> 3;        // row within 8-row group
    int lch = lane & 7;         // destination LDS chunk
    const ushort_t* gA = A  + (size_t)(m0 + wave*32 + lr)*K + (lch ^ lr)*8;
    const ushort_t* gB = Bt + (size_t)(n0 + wave*32 + lr)*K + (lch ^ lr)*8;
    ushort_t* lA = &As[(wave*32)*64];
    ushort_t* lB = &Bs[(wave*32)*64];
    int sx = lane & 7;          // fragment-read swizzle (row&7 == lane&7)

    for (int k0 = 0; k0 < K; k0 += 64){
        #pragma unroll
        for (int i = 0; i < 4; ++i){
            gload16(gA + (size_t)(i*8)*K + k0, lA + i*8*64);
            gload16(gB + (size_t)(i*8)*K + k0, lB + i*8*64);
        }
        __syncthreads();
        #pragma unroll
        for (int s = 0; s < 4; ++s){
            int ch = ((s<<1) | half) ^ sx;
            bf16x8 af[2], bfr[2];
            #pragma unroll
            for (int i=0;i<2;i++) af[i]  = *(const bf16x8*)&As[(wm*64 + i*32 + l31)*64 + ch*8];
            #pragma unroll
            for (int j=0;j<2;j++) bfr[j] = *(const bf16x8*)&Bs[(wn*64 + j*32 + l31)*64 + ch*8];
            #pragma unroll
            for (int i=0;i<2;i++)
                #pragma unroll
                for (int j=0;j<2;j++)
                    acc[i][j] = __builtin_amdgcn_mfma_f32_32x32x16_bf16(af[i], bfr[j], acc[i][j], 0,0,0);
        }
        __syncthreads();
    }

    // C/D layout (32x32): col = lane&31, row = (reg&3) + 8*(reg>>2) + 4*(lane>>5)
    int rowoff = 4*half;
    #pragma unroll
    for (int i=0;i<2;i++){
        #pragma unroll
        for (int j=0;j<2;j++){
            int n = n0 + wn*64 + j*32 + l31;
            #pragma unroll
            for (int reg=0; reg<16; ++reg){
                int m = m0 + wm*64 + i*32 + (reg&3) + 8*(reg>>2) + rowoff;
                float v = acc[i][j][reg];
                size_t idx = (size_t)m*N + n;
                if (MODE == 0){
                    ((ushort_t*)out)[idx] = f2bf(v);
                } else if (MODE == 1){
                    v += bias[n] + resid[idx];
                    ((float*)out)[idx] = v;
                } else if (MODE == 2){
                    v += bias[n];
                    ((ushort_t*)out)[idx] = f2bf(gelu_f(v));
                } else {
                    v += bias[n] + resid[idx];
                    ((float*)out)[idx] = v;
                }
            }
        }
    }
}

// ---------------- Flash attention (causal), S^T formulation ----------------
__global__ __launch_bounds__(256) void attn_kernel(const ushort_t* __restrict__ qkv,
                                                   ushort_t* __restrict__ attn_out){
    __shared__ ushort_t Qs[128*64];    // [q][d], gload chunk-swizzled
    __shared__ ushort_t Ks[64*64];     // [kv][d], gload chunk-swizzled
    __shared__ ushort_t Vts[64][72];   // V^T [d][kv], write-swizzled
    __shared__ ushort_t Ps[128*64];    // P [q][kv], XOR-slotted

    int tid = threadIdx.x;
    int lane = tid & 63, wave = tid >> 6;
    int quad = lane >> 4, l15 = lane & 15;
    int pair = blockIdx.x;         // 0..3
    int bh = blockIdx.y;           // 0..127
    int b = bh >> 4, h = bh & 15;
    size_t tb = (size_t)b * SEQ;

    int lr = lane >> 3, lch = lane & 7;   // gload lane decomposition
    int tr = tid >> 3;                    // V staging: rows 0..31
    int tc = (tid & 7) * 8;
    int sw_w = tid & 7;
    int sx = l15 & 7;                     // fragment-read chunk swizzle

    for (int t = 0; t < 2; ++t){
        int qi = t ? (7 - pair) : pair;

        {
            const ushort_t* gq = qkv + (size_t)(tb + qi*128 + wave*32 + lr)*3072 + h*64 + (lch^lr)*8;
            ushort_t* lq = &Qs[(wave*32)*64];
            #pragma unroll
            for (int p = 0; p < 4; ++p)
                gload16(gq + (size_t)(p*8)*3072, lq + p*8*64);
        }

        f32x4 o_acc[4][2];
        #pragma unroll
        for (int i=0;i<4;i++)
            #pragma unroll
            for (int j=0;j<2;j++) o_acc[i][j] = (f32x4){0.f,0.f,0.f,0.f};
        float m_st[2] = {-1e30f, -1e30f};
        float l_st[2] = {0.f, 0.f};

        int nj = 2*qi + 2;
        for (int j = 0; j < nj; ++j){
            {
                const ushort_t* gk = qkv + (size_t)(tb + j*64 + wave*16 + lr)*3072 + 1024 + h*64 + (lch^lr)*8;
                ushort_t* lk = &Ks[(wave*16)*64];
                gload16(gk, lk);
                gload16(gk + (size_t)8*3072, lk + 8*64);
            }
            #pragma unroll
            for (int p = 0; p < 2; ++p){
                int r = tr + p*32;
                bf16x8 vv = *(const bf16x8*)(qkv + (size_t)(tb + j*64 + r)*3072 + 2048 + h*64 + tc);
                int kcol = r ^ (sw_w << 3);
                #pragma unroll
                for (int c = 0; c < 8; ++c) Vts[tc + c][kcol] = (ushort_t)vv[c];
            }
            __syncthreads();

            // S^T[kv 64][q 32/wave] = K·Q^T
            f32x4 st[4][2];
            #pragma unroll
            for (int mt=0;mt<4;mt++)
                #pragma unroll
                for (int nt=0;nt<2;nt++) st[mt][nt] = (f32x4){0.f,0.f,0.f,0.f};
            #pragma unroll
            for (int kf = 0; kf < 2; ++kf){
                int ch = (kf*4 + quad) ^ sx;
                bf16x8 ak[4], bq[2];
                #pragma unroll
                for (int mt=0;mt<4;mt++) ak[mt] = *(const bf16x8*)&Ks[(mt*16 + l15)*64 + ch*8];
                #pragma unroll
                for (int nt=0;nt<2;nt++) bq[nt] = *(const bf16x8*)&Qs[(wave*32 + nt*16 + l15)*64 + ch*8];
                #pragma unroll
                for (int mt=0;mt<4;mt++)
                    #pragma unroll
                    for (int nt=0;nt<2;nt++)
                        st[mt][nt] = __builtin_amdgcn_mfma_f32_16x16x32_bf16(ak[mt], bq[nt], st[mt][nt], 0,0,0);
            }

            bool need_mask = (j >= 2*qi);
            #pragma unroll
            for (int mt=0;mt<4;mt++)
                #pragma unroll
                for (int nt=0;nt<2;nt++)
                    #pragma unroll
                    for (int r=0;r<4;r++){
                        float s = st[mt][nt][r] * 0.125f;
                        if (need_mask){
                            int kg = j*64 + mt*16 + quad*4 + r;
                            int qg = qi*128 + wave*32 + nt*16 + l15;
                            if (kg > qg) s = -1e30f;
                        }
                        st[mt][nt][r] = s;
                    }

            #pragma unroll
            for (int nt = 0; nt < 2; ++nt){
                float mx = st[0][nt][0];
                #pragma unroll
                for (int mt=0;mt<4;mt++)
                    #pragma unroll
                    for (int r=0;r<4;r++) mx = fmaxf(mx, st[mt][nt][r]);
                mx = fmaxf(mx, __shfl_xor(mx, 16));
                mx = fmaxf(mx, __shfl_xor(mx, 32));
                float mnew = fmaxf(m_st[nt], mx);
                float al = __expf(m_st[nt] - mnew);
                float ps = 0.f;
                #pragma unroll
                for (int mt=0;mt<4;mt++)
                    #pragma unroll
                    for (int r=0;r<4;r++){
                        float p = __expf(st[mt][nt][r] - mnew);
                        st[mt][nt][r] = p;
                        ps += p;
                    }
                ps += __shfl_xor(ps, 16);
                ps += __shfl_xor(ps, 32);
                l_st[nt] = l_st[nt]*al + ps;
                m_st[nt] = mnew;
                #pragma unroll
                for (int mtd=0;mtd<4;mtd++)
                    #pragma unroll
                    for (int r=0;r<4;r++) o_acc[mtd][nt][r] *= al;
                #pragma unroll
                for (int mt=0;mt<4;mt++){
                    int slot = (mt*2 + (quad>>1)) ^ sx;
                    ushort4 pk;
                    pk.x = f2bf(st[mt][nt][0]); pk.y = f2bf(st[mt][nt][1]);
                    pk.z = f2bf(st[mt][nt][2]); pk.w = f2bf(st[mt][nt][3]);
                    *(ushort4*)&Ps[(wave*32 + nt*16 + l15)*64 + slot*8 + (quad&1)*4] = pk;
                }
            }

            // O^T[d 64][q 32/wave] += V^T·P^T
            #pragma unroll
            for (int kf = 0; kf < 2; ++kf){
                bf16x8 av[4], bp[2];
                #pragma unroll
                for (int mtd=0;mtd<4;mtd++){
                    int d = mtd*16 + l15;
                    int col = (kf*32 + quad*8) ^ (((d >> 3) & 7) << 3);
                    av[mtd] = *(const bf16x8*)&Vts[d][col];
                }
                #pragma unroll
                for (int nt=0;nt<2;nt++){
                    int ch = (kf*4 + quad) ^ sx;
                    bp[nt] = *(const bf16x8*)&Ps[(wave*32 + nt*16 + l15)*64 + ch*8];
                }
                #pragma unroll
                for (int mtd=0;mtd<4;mtd++)
                    #pragma unroll
                    for (int nt=0;nt<2;nt++)
                        o_acc[mtd][nt] = __builtin_amdgcn_mfma_f32_16x16x32_bf16(av[mtd], bp[nt], o_acc[mtd][nt], 0,0,0);
            }
            __syncthreads();
        }

        #pragma unroll
        for (int nt = 0; nt < 2; ++nt){
            float inv = 1.0f / l_st[nt];
            size_t tok = tb + qi*128 + wave*32 + nt*16 + l15;
            #pragma unroll
            for (int mtd = 0; mtd < 4; ++mtd){
                ushort4 ok;
                ok.x = f2bf(o_acc[mtd][nt][0]*inv); ok.y = f2bf(o_acc[mtd][nt][1]*inv);
                ok.z = f2bf(o_acc[mtd][nt][2]*inv); ok.w = f2bf(o_acc[mtd][nt][3]*inv);
                *(ushort4*)(attn_out + tok*EMB + h*64 + mtd*16 + quad*4) = ok;
            }
        }
    }
}

extern "C" void kernel_launch(void* const* d_in, const int* in_sizes, int n_in,
                              void* d_out, int out_size, void* d_ws, size_t ws_size,
                              hipStream_t stream){
    const float* x      = (const float*)d_in[0];
    const float* ln1_g  = (const float*)d_in[1];
    const float* ln1_b  = (const float*)d_in[2];
    const float* wq     = (const float*)d_in[3];
    const float* wk     = (const float*)d_in[4];
    const float* wv     = (const float*)d_in[5];
    const float* w_proj = (const float*)d_in[6];
    const float* b_proj = (const float*)d_in[7];
    const float* ln2_g  = (const float*)d_in[8];
    const float* ln2_b  = (const float*)d_in[9];
    const float* w1     = (const float*)d_in[10];
    const float* b1     = (const float*)d_in[11];
    const float* w2     = (const float*)d_in[12];
    const float* b2     = (const float*)d_in[13];
    float* outp = (float*)d_out;

    char* ws = (char*)d_ws;
    size_t off = 0;
    auto alloc = [&](size_t bytes)->char*{ char* p = ws + off; off += (bytes + 255) & ~255ULL; return p; };
    ushort_t* wqkv_t = (ushort_t*)alloc((size_t)3072*1024*2);
    ushort_t* wproj_t= (ushort_t*)alloc((size_t)1024*1024*2);
    ushort_t* w1_t   = (ushort_t*)alloc((size_t)4096*1024*2);
    ushort_t* w2_t   = (ushort_t*)alloc((size_t)1024*4096*2);
    ushort_t* qkv    = (ushort_t*)alloc((size_t)ROWS*3072*2);
    ushort_t* hbuf   = (ushort_t*)alloc((size_t)ROWS*1024*2);
    float*    out32  = (float*)  alloc((size_t)ROWS*1024*4);
    ushort_t* mid    = (ushort_t*)alloc((size_t)ROWS*4096*2);
    ushort_t* h1 = hbuf;
    ushort_t* attn = hbuf;   // h1 dead after qkv GEMM
    ushort_t* h2 = qkv;      // qkv dead after attention

    dim3 blk(256);
    // blocks: 8192 LN1 rows + 3072 (wq/wk/wv) + 1024 (wproj) + 4096 (w1) + 4096 (w2)
    prep_kernel<<<dim3(20480), blk, 0, stream>>>(x, ln1_g, ln1_b, h1,
                                                 wq, wk, wv, w_proj, w1, w2,
                                                 wqkv_t, wproj_t, w1_t, w2_t);
    gemm_kernel<0><<<dim3(MT*(3072/128)), blk, 0, stream>>>(h1, wqkv_t, nullptr, nullptr, qkv, ROWS, 3072, 1024);
    attn_kernel<<<dim3(4,128), blk, 0, stream>>>(qkv, attn);
    gemm_kernel<1><<<dim3(MT*(1024/128)), blk, 0, stream>>>(attn, wproj_t, b_proj, x, out32, ROWS, 1024, 1024);
    ln_kernel<<<ROWS, blk, 0, stream>>>(out32, ln2_g, ln2_b, h2);
    gemm_kernel<2><<<dim3(MT*(4096/128)), blk, 0, stream>>>(h2, w1_t, b1, nullptr, mid, ROWS, 4096, 1024);
    gemm_kernel<3><<<dim3(MT*(1024/128)), blk, 0, stream>>>(mid, w2_t, b2, out32, outp, ROWS, 1024, 4096);
}